// Round 9
// baseline (896.991 us; speedup 1.0000x reference)
//
#include <hip/hip_runtime.h>
#include <hip/hip_bf16.h>

// ---------------------------------------------------------------------------
// Star-Transformer 2-layer forward. bf16 MFMA GEMMs (fp32 accum), bf16
// attention operands, fused residual-adds in attention, parallel 2-stage BN.
// Round 9: GEMM = 4 INDEPENDENT waves per 256-thread workgroup, each wave
// owns one 64x64 tile, LDS-free, barrier-free. Evidence from rounds 1-8:
// concurrent workgroups/CU is capped at ~2-3 regardless of LDS/VGPR
// (fp32 2.6, 128-tile 2, single-wave 3) -> fill each scarce wg slot with
// 4 decoupled latency-hiding wave streams instead of 1 (r7/8) or 4
// barrier-coupled ones (r4-6).
// Row-major activations (row, channel), C=256 contiguous.
// ---------------------------------------------------------------------------

using bf16 = __hip_bfloat16;
typedef __attribute__((ext_vector_type(8))) short bf16x8v;
typedef __attribute__((ext_vector_type(4))) float f32x4;

namespace {
constexpr int kBT = 1024;
constexpr int kC = 256;
constexpr int kV = 17;
constexpr int kT = 256;
constexpr int kDIN = 1024;
constexpr int kRows = kBT * kV;                  // 17408
constexpr int kRowsX = kRows + kBT;              // 18432 (nodes + relay tail)
constexpr float kInvSqrtDk = 0.17677669529663687f;
constexpr size_t SZ_BIG = (size_t)kRows * kC;
constexpr size_t SZ_SM = (size_t)kBT * kC;
}  // namespace

__constant__ int c_nbi[17][5] = {
    {0, 1, 2, 5, 6},   {0, 1, 3, 0, 0},   {0, 2, 4, 0, 0},  {1, 3, 0, 0, 0},
    {2, 4, 0, 0, 0},   {0, 5, 7, 11, 0},  {0, 6, 8, 12, 0}, {5, 7, 9, 0, 0},
    {6, 8, 12, 0, 0},  {7, 9, 0, 0, 0},   {8, 10, 0, 0, 0}, {8, 11, 13, 0, 0},
    {10, 12, 14, 0, 0},{11, 13, 15, 0, 0},{12, 14, 16, 0, 0},
    {13, 15, 0, 0, 0}, {14, 16, 0, 0, 0}};
__constant__ int c_ncnt[17] = {5, 3, 3, 2, 2, 4, 4, 3, 3, 2, 2, 3, 3, 3, 3, 2, 2};

__device__ inline float bf2f(unsigned short s) {
  unsigned int u = ((unsigned int)s) << 16;
  float f;
  __builtin_memcpy(&f, &u, 4);
  return f;
}
__device__ inline unsigned short f2bf(float f) {
  unsigned int u;
  __builtin_memcpy(&u, &f, 4);
  unsigned int r = (u + 0x7fffu + ((u >> 16) & 1u)) >> 16;  // RNE
  return (unsigned short)r;
}
__device__ inline float4 ldbf4(const bf16* p) {
  ushort4 u = *(const ushort4*)p;
  return make_float4(bf2f(u.x), bf2f(u.y), bf2f(u.z), bf2f(u.w));
}
__device__ inline void stbf4(bf16* p, float4 v) {
  ushort4 u = make_ushort4(f2bf(v.x), f2bf(v.y), f2bf(v.z), f2bf(v.w));
  *(ushort4*)p = u;
}
__device__ inline float dot4(float4 a, float4 b) {
  return a.x * b.x + a.y * b.y + a.z * b.z + a.w * b.w;
}

// ---- bf16 MFMA GEMM: C = A[M,K]@W[N,K]^T + bias (+res) ----
// flags: 1=relu, 2=fp32 out, 4=bf16 out
// 256-thread workgroup = 4 INDEPENDENT waves; wave w owns flattened tile
// blockIdx.x*4+w. No LDS, no barriers: fragments loaded straight from
// global (lane&15 = row/col, (lane>>4)*8 = k -> one dwordx4 per fragment).
__global__ __launch_bounds__(256) void k_mfma_gemm(
    const bf16* __restrict__ A, const bf16* __restrict__ W,
    const float* __restrict__ bias, const float* __restrict__ res,
    float* __restrict__ outF, bf16* __restrict__ outB,
    int M, int N, int K, int flags) {
  const int lane = threadIdx.x & 63;
  const int wave = threadIdx.x >> 6;
  const int nt = N >> 6;                 // tiles per C-row
  const int total = (M >> 6) * nt;
  const int t = blockIdx.x * 4 + wave;
  if (t >= total) return;
  const int row0 = (t / nt) * 64;
  const int col0 = (t - (t / nt) * nt) * 64;

  const int fr = lane & 15;        // row (A) / col (W) within 16-tile
  const int fk = (lane >> 4) * 8;  // k offset (8 elems = 16 B)

  const bf16* ap = A + (size_t)(row0 + fr) * K + fk;
  const bf16* bp = W + (size_t)(col0 + fr) * K + fk;
  const size_t a16 = (size_t)16 * K;  // 16-row stride

  f32x4 acc[4][4];
#pragma unroll
  for (int i = 0; i < 4; ++i)
#pragma unroll
    for (int j = 0; j < 4; ++j) acc[i][j] = (f32x4){0.f, 0.f, 0.f, 0.f};

#pragma unroll 2
  for (int k0 = 0; k0 < K; k0 += 32) {
    bf16x8v af[4], bfv[4];
#pragma unroll
    for (int i = 0; i < 4; ++i)
      af[i] = *(const bf16x8v*)(ap + (size_t)i * a16 + k0);
#pragma unroll
    for (int j = 0; j < 4; ++j)
      bfv[j] = *(const bf16x8v*)(bp + (size_t)j * a16 + k0);
#pragma unroll
    for (int i = 0; i < 4; ++i)
#pragma unroll
      for (int j = 0; j < 4; ++j)
        acc[i][j] = __builtin_amdgcn_mfma_f32_16x16x32_bf16(af[i], bfv[j],
                                                            acc[i][j], 0, 0, 0);
  }

#pragma unroll
  for (int j = 0; j < 4; ++j) {
    int col = col0 + j * 16 + fr;
    float bv = bias ? bias[col] : 0.f;
#pragma unroll
    for (int i = 0; i < 4; ++i) {
      int rowb = row0 + i * 16 + (lane >> 4) * 4;
#pragma unroll
      for (int r = 0; r < 4; ++r) {
        size_t row = (size_t)(rowb + r);
        float v = acc[i][j][r] + bv;
        if (res) v += res[row * N + col];
        if (flags & 1) v = fmaxf(v, 0.f);
        if (flags & 2) outF[row * N + col] = v;
        if (flags & 4) outB[row * N + col] = __float2bfloat16(v);
      }
    }
  }
}

// data (B,C,V,T) -> nodes fp32 rows + embs bf16 rows
__global__ __launch_bounds__(256) void k_xform_in(const float* __restrict__ data,
                                                  float* __restrict__ nodes,
                                                  bf16* __restrict__ embs_bf) {
  __shared__ float tile[32][33];
  int ct = blockIdx.x * 32, tt = blockIdx.y * 32;
  int bv = blockIdx.z;
  int b = bv / kV, v = bv - b * kV;
  int tx = threadIdx.x & 31, ty = threadIdx.x >> 5;
  for (int i = ty; i < 32; i += 8)
    tile[i][tx] = data[(((size_t)b * kC + ct + i) * kV + v) * kT + tt + tx];
  __syncthreads();
  for (int i = ty; i < 32; i += 8) {
    size_t s = (size_t)b * kT + tt + i;
    size_t idx = (s * kV + v) * kC + ct + tx;
    float val = tile[tx][i];
    nodes[idx] = val;
    embs_bf[idx] = __float2bfloat16(val);
  }
}

__global__ __launch_bounds__(256) void k_xform_out(const float* __restrict__ nodes,
                                                   float* __restrict__ out) {
  __shared__ float tile[32][33];
  int ct = blockIdx.x * 32, tt = blockIdx.y * 32;
  int bv = blockIdx.z;
  int b = bv / kV, v = bv - b * kV;
  int tx = threadIdx.x & 31, ty = threadIdx.x >> 5;
  for (int i = ty; i < 32; i += 8) {
    size_t s = (size_t)b * kT + tt + i;
    tile[i][tx] = nodes[(s * kV + v) * kC + ct + tx];
  }
  __syncthreads();
  for (int i = ty; i < 32; i += 8)
    out[(((size_t)b * kC + ct + i) * kV + v) * kT + tt + tx] = tile[tx][i];
}

// relay init: mean over v; write relay fp32 + relay_bf + relay0_bf (float4)
__global__ __launch_bounds__(256) void k_relay_init(const float* __restrict__ nodes,
                                                    float* __restrict__ relay,
                                                    bf16* __restrict__ relay_bf,
                                                    bf16* __restrict__ relay0_bf) {
  int t = threadIdx.x;
  int s = blockIdx.x * 4 + (t >> 6);
  int c4 = (t & 63) * 4;
  float4 acc = make_float4(0.f, 0.f, 0.f, 0.f);
#pragma unroll
  for (int v = 0; v < kV; ++v) {
    float4 x = *(const float4*)(nodes + ((size_t)s * kV + v) * kC + c4);
    acc.x += x.x; acc.y += x.y; acc.z += x.z; acc.w += x.w;
  }
  float4 r = make_float4(acc.x / 17.f, acc.y / 17.f, acc.z / 17.f, acc.w / 17.f);
  size_t i = (size_t)s * kC + c4;
  *(float4*)(relay + i) = r;
  stbf4(relay_bf + i, r);
  stbf4(relay0_bf + i, r);
}

// layernorm: wave per row, float4; writes fp32 + bf16
__global__ __launch_bounds__(256) void k_layernorm(const float* __restrict__ X,
                                                   const float* __restrict__ g,
                                                   const float* __restrict__ b,
                                                   float* __restrict__ O,
                                                   bf16* __restrict__ Ob) {
  int t = threadIdx.x;
  int row = blockIdx.x * 4 + (t >> 6);
  int c4 = (t & 63) * 4;
  size_t i = (size_t)row * kC + c4;
  float4 x = *(const float4*)(X + i);
  float s = x.x + x.y + x.z + x.w;
  float q = dot4(x, x);
#pragma unroll
  for (int o = 32; o >= 1; o >>= 1) {
    s += __shfl_xor(s, o);
    q += __shfl_xor(q, o);
  }
  float m = s * (1.f / 256.f);
  float var = q * (1.f / 256.f) - m * m;
  float rs = rsqrtf(var + 1e-6f);
  float4 g4 = *(const float4*)(g + c4);
  float4 b4 = *(const float4*)(b + c4);
  float4 o4 = make_float4((x.x - m) * rs * g4.x + b4.x,
                          (x.y - m) * rs * g4.y + b4.y,
                          (x.z - m) * rs * g4.z + b4.z,
                          (x.w - m) * rs * g4.w + b4.w);
  *(float4*)(O + i) = o4;
  stbf4(Ob + i, o4);
}

// satellite attention, wave per (s,l). qkv bf16 [q|kx|vx] stride 768;
// akav bf16 [ak|av] stride 512, rows 0..17407 = per-node, 17408+s = relay.
// z (fp32, stride 256) updated in place: z = z + att.
__global__ __launch_bounds__(256) void k_attn_sat(const bf16* __restrict__ qkv,
                                                  const bf16* __restrict__ akav,
                                                  float* __restrict__ z) {
  int t = threadIdx.x;
  int rl = blockIdx.x * 4 + (t >> 6);
  int lane = t & 63;
  int s = rl / kV, l = rl - s * kV;
  int c4 = lane * 4;
  float4 q = ldbf4(qkv + (size_t)rl * 768 + c4);
  int cnt = c_ncnt[l];
  float sc[7];
  int nrow[5];
#pragma unroll
  for (int w = 0; w < 5; ++w) {
    nrow[w] = s * kV + c_nbi[l][w];
    float4 k = ldbf4(qkv + (size_t)nrow[w] * 768 + 256 + c4);
    float p = dot4(q, k);
    p += __shfl_xor(p, 1, 8);
    p += __shfl_xor(p, 2, 8);
    p += __shfl_xor(p, 4, 8);
    sc[w] = (w < cnt) ? p * kInvSqrtDk : -1e30f;
  }
  {
    float4 k = ldbf4(akav + (size_t)rl * 512 + c4);
    float p = dot4(q, k);
    p += __shfl_xor(p, 1, 8);
    p += __shfl_xor(p, 2, 8);
    p += __shfl_xor(p, 4, 8);
    sc[5] = p * kInvSqrtDk;
  }
  {
    float4 k = ldbf4(akav + (size_t)(kRows + s) * 512 + c4);
    float p = dot4(q, k);
    p += __shfl_xor(p, 1, 8);
    p += __shfl_xor(p, 2, 8);
    p += __shfl_xor(p, 4, 8);
    sc[6] = p * kInvSqrtDk;
  }
  float mx = sc[0];
#pragma unroll
  for (int w = 1; w < 7; ++w) mx = fmaxf(mx, sc[w]);
  float den = 0.f;
#pragma unroll
  for (int w = 0; w < 7; ++w) {
    sc[w] = __expf(sc[w] - mx);
    den += sc[w];
  }
  float inv = 1.f / den;
  float4 acc = make_float4(0.f, 0.f, 0.f, 0.f);
#pragma unroll
  for (int w = 0; w < 5; ++w) {
    float4 v = ldbf4(qkv + (size_t)nrow[w] * 768 + 512 + c4);
    acc.x += sc[w] * v.x; acc.y += sc[w] * v.y;
    acc.z += sc[w] * v.z; acc.w += sc[w] * v.w;
  }
  {
    float4 v = ldbf4(akav + (size_t)rl * 512 + 256 + c4);
    acc.x += sc[5] * v.x; acc.y += sc[5] * v.y;
    acc.z += sc[5] * v.z; acc.w += sc[5] * v.w;
  }
  {
    float4 v = ldbf4(akav + (size_t)(kRows + s) * 512 + 256 + c4);
    acc.x += sc[6] * v.x; acc.y += sc[6] * v.y;
    acc.z += sc[6] * v.z; acc.w += sc[6] * v.w;
  }
  size_t zi = (size_t)rl * kC + c4;
  float4 xv = *(const float4*)(z + zi);
  *(float4*)(z + zi) = make_float4(xv.x + acc.x * inv, xv.y + acc.y * inv,
                                   xv.z + acc.z * inv, xv.w + acc.w * inv);
}

// relay attention, wave per sample. kvq bf16 [k|v|q] stride 768; node rows
// s*17+j, relay row kRows+s. zr = relay + att (fp32).
__global__ __launch_bounds__(256) void k_attn_relay(const bf16* __restrict__ kvq,
                                                    const float* __restrict__ relay,
                                                    float* __restrict__ zr) {
  int t = threadIdx.x;
  int s = blockIdx.x * 4 + (t >> 6);
  int lane = t & 63;
  int c4 = lane * 4;
  float4 q = ldbf4(kvq + (size_t)(kRows + s) * 768 + 512 + c4);
  float sc[18];
  {
    float4 k = ldbf4(kvq + (size_t)(kRows + s) * 768 + c4);
    float p = dot4(q, k);
    p += __shfl_xor(p, 1, 8);
    p += __shfl_xor(p, 2, 8);
    p += __shfl_xor(p, 4, 8);
    sc[0] = p * kInvSqrtDk;
  }
#pragma unroll
  for (int j = 0; j < kV; ++j) {
    float4 k = ldbf4(kvq + (size_t)(s * kV + j) * 768 + c4);
    float p = dot4(q, k);
    p += __shfl_xor(p, 1, 8);
    p += __shfl_xor(p, 2, 8);
    p += __shfl_xor(p, 4, 8);
    sc[j + 1] = p * kInvSqrtDk;
  }
  float mx = sc[0];
#pragma unroll
  for (int j = 1; j < 18; ++j) mx = fmaxf(mx, sc[j]);
  float den = 0.f;
#pragma unroll
  for (int j = 0; j < 18; ++j) {
    sc[j] = __expf(sc[j] - mx);
    den += sc[j];
  }
  float inv = 1.f / den;
  float4 acc;
  {
    float4 v = ldbf4(kvq + (size_t)(kRows + s) * 768 + 256 + c4);
    acc = make_float4(sc[0] * v.x, sc[0] * v.y, sc[0] * v.z, sc[0] * v.w);
  }
#pragma unroll
  for (int j = 0; j < kV; ++j) {
    float4 v = ldbf4(kvq + (size_t)(s * kV + j) * 768 + 256 + c4);
    acc.x += sc[j + 1] * v.x; acc.y += sc[j + 1] * v.y;
    acc.z += sc[j + 1] * v.z; acc.w += sc[j + 1] * v.w;
  }
  size_t i = (size_t)s * kC + c4;
  float4 r = *(const float4*)(relay + i);
  *(float4*)(zr + i) = make_float4(r.x + acc.x * inv, r.y + acc.y * inv,
                                   r.z + acc.z * inv, r.w + acc.w * inv);
}

// BN stage 1: 16 rows per block, scalar coalesced
__global__ __launch_bounds__(256) void k_bn_partial(const float* __restrict__ A,
                                                    float* __restrict__ part,
                                                    int nb) {
  int c = threadIdx.x, blk = blockIdx.x;
  int lo = blk * 16;
  float s = 0.f, q = 0.f;
#pragma unroll
  for (int r = 0; r < 16; ++r) {
    float v = A[(size_t)(lo + r) * kC + c];
    s += v;
    q += v * v;
  }
  part[(size_t)blk * kC + c] = s;
  part[(size_t)(nb + blk) * kC + c] = q;
}

// BN stage 2: block per channel; 256 threads strided over nb partials,
// shuffle+LDS block reduction.
__global__ __launch_bounds__(256) void k_bn_finalize(const float* __restrict__ part,
                                                     int nb, float inv_n,
                                                     const float* __restrict__ g,
                                                     const float* __restrict__ b,
                                                     float* __restrict__ scale,
                                                     float* __restrict__ shift) {
  int c = blockIdx.x;
  int t = threadIdx.x;
  float s = 0.f, q = 0.f;
  for (int i = t; i < nb; i += 256) {
    s += part[(size_t)i * kC + c];
    q += part[(size_t)(nb + i) * kC + c];
  }
#pragma unroll
  for (int o = 32; o >= 1; o >>= 1) {
    s += __shfl_xor(s, o);
    q += __shfl_xor(q, o);
  }
  __shared__ float ws[4], wq[4];
  int wid = t >> 6;
  if ((t & 63) == 0) { ws[wid] = s; wq[wid] = q; }
  __syncthreads();
  if (t == 0) {
    float S = ws[0] + ws[1] + ws[2] + ws[3];
    float Q = wq[0] + wq[1] + wq[2] + wq[3];
    float m = S * inv_n;
    float var = Q * inv_n - m * m;
    float sc = g[c] * rsqrtf(var + 1e-5f);
    scale[c] = sc;
    shift[c] = b[c] - m * sc;
  }
}

// BN stage 3: 4 rows/block, float4; writes fp32 and/or bf16
__global__ __launch_bounds__(256) void k_bn_apply(const float* __restrict__ Z,
                                                  const float* __restrict__ scale,
                                                  const float* __restrict__ shift,
                                                  float* __restrict__ outF,
                                                  bf16* __restrict__ outB,
                                                  int leaky) {
  int t = threadIdx.x;
  int row = blockIdx.x * 4 + (t >> 6);
  int c4 = (t & 63) * 4;
  size_t i = (size_t)row * kC + c4;
  float4 z = *(const float4*)(Z + i);
  float4 sc = *(const float4*)(scale + c4);
  float4 sh = *(const float4*)(shift + c4);
  float4 v = make_float4(z.x * sc.x + sh.x, z.y * sc.y + sh.y,
                         z.z * sc.z + sh.z, z.w * sc.w + sh.w);
  if (leaky) {
    v.x = (v.x > 0.f) ? v.x : 0.01f * v.x;
    v.y = (v.y > 0.f) ? v.y : 0.01f * v.y;
    v.z = (v.z > 0.f) ? v.z : 0.01f * v.z;
    v.w = (v.w > 0.f) ? v.w : 0.01f * v.w;
  }
  if (outF) *(float4*)(outF + i) = v;
  if (outB) stbf4(outB + i, v);
}

// batched f32->bf16 conversion (16 chunks, one launch)
struct CvtTab {
  const float* src[16];
  bf16* dst[16];
  int n[16];
};
__global__ __launch_bounds__(256) void k_cvt_multi(CvtTab t) {
  int c = blockIdx.y;
  int i = (blockIdx.x * 256 + threadIdx.x) * 4;
  if (i >= t.n[c]) return;
  float4 v = *(const float4*)(t.src[c] + i);
  stbf4(t.dst[c] + i, v);
}

// batched bias copies (12 segments of 256)
struct BiasTab {
  const float* src[12];
  float* dst[12];
};
__global__ __launch_bounds__(256) void k_bias_cat(BiasTab t) {
  t.dst[blockIdx.x][threadIdx.x] = t.src[blockIdx.x][threadIdx.x];
}

extern "C" void kernel_launch(void* const* d_in, const int* in_sizes, int n_in,
                              void* d_out, int out_size, void* d_ws, size_t ws_size,
                              hipStream_t stream) {
  const float* data = (const float*)d_in[0];
  const float* ln_g = (const float*)d_in[1];
  const float* ln_b = (const float*)d_in[2];
  const float* jq_w = (const float*)d_in[3];
  const float* jq_b = (const float*)d_in[4];
  const float* jk_w = (const float*)d_in[5];
  const float* jk_b = (const float*)d_in[6];
  const float* jv_w = (const float*)d_in[7];
  const float* jv_b = (const float*)d_in[8];
  const float* jbn_g = (const float*)d_in[9];
  const float* jbn_b = (const float*)d_in[10];
  const float* jf1_w = (const float*)d_in[11];
  const float* jf1_b = (const float*)d_in[12];
  const float* jf2_w = (const float*)d_in[13];
  const float* jf2_b = (const float*)d_in[14];
  const float* jfbn_g = (const float*)d_in[15];
  const float* jfbn_b = (const float*)d_in[16];
  const float* rq_w = (const float*)d_in[17];
  const float* rq_b = (const float*)d_in[18];
  const float* rk_w = (const float*)d_in[19];
  const float* rk_b = (const float*)d_in[20];
  const float* rv_w = (const float*)d_in[21];
  const float* rv_b = (const float*)d_in[22];
  const float* rbn_g = (const float*)d_in[23];
  const float* rbn_b = (const float*)d_in[24];
  const float* rf1_w = (const float*)d_in[25];
  const float* rf1_b = (const float*)d_in[26];
  const float* rf2_w = (const float*)d_in[27];
  const float* rf2_b = (const float*)d_in[28];
  const float* rfbn_g = (const float*)d_in[29];
  const float* rfbn_b = (const float*)d_in[30];
  float* out = (float*)d_out;

  // ---- arena ----
  float* f = (float*)d_ws;
  float* nodes = f;    f += SZ_BIG;           // pre-LN nodes; 'ret' mid-layer
  float* xn = f;       f += SZ_BIG;           // LN out -> z -> y2
  float* relay = f;    f += SZ_SM;
  float* zr = f;       f += SZ_SM;
  float* retr = f;     f += SZ_SM;
  float* yr2 = f;      f += SZ_SM;
  float* part = f;     f += 2 * 1088 * kC;
  float* scale = f;    f += kC;
  float* shift = f;    f += kC;
  float* cb_jqkv = f;  f += 2 * 768;
  float* cb_rkvq = f;  f += 2 * 768;

  bf16* bfa = (bf16*)f;
  bf16* embs_bf = bfa;   bfa += (size_t)kRowsX * kC;  // tail = relay0_bf
  bf16* act_bf = bfa;    bfa += (size_t)kRowsX * kC;  // tail = relay_bf
  bf16* big_bf = bfa;    bfa += (size_t)kRows * kDIN; // qkv -> h -> kvq_all
  bf16* akav_bf = bfa;   bfa += (size_t)kRowsX * 512;
  bf16* hr_bf = bfa;     bfa += (size_t)kBT * kDIN;
  bf16* retr_bf = bfa;   bfa += SZ_SM;
  bf16* Wjqkv = bfa;     bfa += 2 * 768 * 256;
  bf16* Wjf1 = bfa;      bfa += 2 * 1024 * 256;
  bf16* Wjf2 = bfa;      bfa += 2 * 256 * 1024;
  bf16* Wrkvq = bfa;     bfa += 2 * 768 * 256;
  bf16* Wrf1 = bfa;      bfa += 2 * 1024 * 256;
  bf16* Wrf2 = bfa;      bfa += 2 * 256 * 1024;

  bf16* relay0_bf = embs_bf + SZ_BIG;   // rows kRows..kRowsX-1
  bf16* relay_bf = act_bf + SZ_BIG;
  bf16* qkv_bf = big_bf;                // 17408 x 768
  bf16* h_bf = big_bf;                  // 17408 x 1024
  bf16* kvq_bf = big_bf;                // 18432 x 768
  float* y2 = xn;

  auto gemm = [&](const bf16* A, const bf16* W, const float* bias,
                  const float* res, float* oF, bf16* oB, int M, int N, int K,
                  int flags) {
    int total = (M / 64) * (N / 64);
    k_mfma_gemm<<<(total + 3) / 4, 256, 0, stream>>>(A, W, bias, res, oF, oB,
                                                     M, N, K, flags);
  };
  auto bn = [&](const float* Z, int rows, const float* g_, const float* b_,
                float* dstF, bf16* dstB, int leaky) {
    int nb = rows / 16;
    k_bn_partial<<<nb, 256, 0, stream>>>(Z, part, nb);
    k_bn_finalize<<<kC, 256, 0, stream>>>(part, nb, 1.f / rows, g_, b_, scale,
                                          shift);
    k_bn_apply<<<rows / 4, 256, 0, stream>>>(Z, scale, shift, dstF, dstB, leaky);
  };

  // ---- weight conversion (one launch) ----
  {
    CvtTab t;
    for (int i = 0; i < 2; ++i) {
      const size_t om = (size_t)i * kC * kC;
      const float* s6[6] = {jq_w + om, jk_w + om, jv_w + om,
                            rk_w + om, rv_w + om, rq_w + om};
      bf16* d6[6] = {Wjqkv + (size_t)i * 768 * 256,
                     Wjqkv + (size_t)i * 768 * 256 + 65536,
                     Wjqkv + (size_t)i * 768 * 256 + 131072,
                     Wrkvq + (size_t)i * 768 * 256,
                     Wrkvq + (size_t)i * 768 * 256 + 65536,
                     Wrkvq + (size_t)i * 768 * 256 + 131072};
      for (int j = 0; j < 6; ++j) {
        t.src[i * 6 + j] = s6[j];
        t.dst[i * 6 + j] = d6[j];
        t.n[i * 6 + j] = 65536;
      }
    }
    t.src[12] = jf1_w; t.dst[12] = Wjf1; t.n[12] = 524288;
    t.src[13] = jf2_w; t.dst[13] = Wjf2; t.n[13] = 524288;
    t.src[14] = rf1_w; t.dst[14] = Wrf1; t.n[14] = 524288;
    t.src[15] = rf2_w; t.dst[15] = Wrf2; t.n[15] = 524288;
    k_cvt_multi<<<dim3(512, 16), 256, 0, stream>>>(t);
  }
  {
    BiasTab t;
    for (int i = 0; i < 2; ++i) {
      const float* s6[6] = {jq_b + (size_t)i * kC, jk_b + (size_t)i * kC,
                            jv_b + (size_t)i * kC, rk_b + (size_t)i * kC,
                            rv_b + (size_t)i * kC, rq_b + (size_t)i * kC};
      float* d6[6] = {cb_jqkv + i * 768,       cb_jqkv + i * 768 + 256,
                      cb_jqkv + i * 768 + 512, cb_rkvq + i * 768,
                      cb_rkvq + i * 768 + 256, cb_rkvq + i * 768 + 512};
      for (int j = 0; j < 6; ++j) {
        t.src[i * 6 + j] = s6[j];
        t.dst[i * 6 + j] = d6[j];
      }
    }
    k_bias_cat<<<12, 256, 0, stream>>>(t);
  }

  k_xform_in<<<dim3(8, 8, 4 * kV), 256, 0, stream>>>(data, nodes, embs_bf);
  k_relay_init<<<kBT / 4, 256, 0, stream>>>(nodes, relay, relay_bf, relay0_bf);

  for (int i = 0; i < 2; ++i) {
    const size_t ob = (size_t)i * kC, ofb1 = (size_t)i * kDIN;
    const bf16* Wj = Wjqkv + (size_t)i * 768 * 256;
    const bf16* Wr = Wrkvq + (size_t)i * 768 * 256;
    const bf16* Wf1 = Wjf1 + (size_t)i * 1024 * 256;
    const bf16* Wf2 = Wjf2 + (size_t)i * 256 * 1024;
    const bf16* Wg1 = Wrf1 + (size_t)i * 1024 * 256;
    const bf16* Wg2 = Wrf2 + (size_t)i * 256 * 1024;
    const float* cbj = cb_jqkv + i * 768;
    const float* cbr = cb_rkvq + i * 768;

    // ---- satellite ----
    k_layernorm<<<kRows / 4, 256, 0, stream>>>(nodes, ln_g + ob, ln_b + ob, xn,
                                               act_bf);
    gemm(act_bf, Wj, cbj, nullptr, nullptr, qkv_bf, kRows, 768, 256, 4);
    gemm(embs_bf, Wj + 256 * 256, cbj + 256, nullptr, nullptr, akav_bf, kRowsX,
         512, 256, 4);
    k_attn_sat<<<kRows / 4, 256, 0, stream>>>(qkv_bf, akav_bf, xn);
    bn(xn, kRows, jbn_g + ob, jbn_b + ob, nodes, act_bf, 0);  // ret -> nodes
    gemm(act_bf, Wf1, jf1_b + ofb1, nullptr, nullptr, h_bf, kRows, 1024, 256,
         4 | 1);
    gemm(h_bf, Wf2, jf2_b + ob, nodes, y2, nullptr, kRows, 256, 1024, 2);
    bn(y2, kRows, jfbn_g + ob, jfbn_b + ob, nodes, act_bf, 1);

    // ---- relay ----
    gemm(act_bf, Wr, cbr, nullptr, nullptr, kvq_bf, kRowsX, 768, 256, 4);
    k_attn_relay<<<kBT / 4, 256, 0, stream>>>(kvq_bf, relay, zr);
    bn(zr, kBT, rbn_g + ob, rbn_b + ob, retr, retr_bf, 0);
    gemm(retr_bf, Wg1, rf1_b + ofb1, nullptr, nullptr, hr_bf, kBT, 1024, 256,
         4 | 1);
    gemm(hr_bf, Wg2, rf2_b + ob, retr, yr2, nullptr, kBT, 256, 1024, 2);
    bn(yr2, kBT, rfbn_g + ob, rfbn_b + ob, relay, relay_bf, 1);
  }

  k_xform_out<<<dim3(8, 8, 4 * kV), 256, 0, stream>>>(nodes, out);
  (void)in_sizes; (void)n_in; (void)out_size; (void)ws_size;
}

// Round 10
// 488.003 us; speedup vs baseline: 1.8381x; 1.8381x over previous
//
#include <hip/hip_runtime.h>
#include <hip/hip_bf16.h>

// ---------------------------------------------------------------------------
// Star-Transformer 2-layer forward — SATELLITE BRANCH ONLY.
// Key round-10 insight: the reference's relay (_sru) branch is DEAD CODE for
// the output — ax is built from embs + the INITIAL relay before the loop,
// _sju never reads the evolving relay, and only `nodes` is returned. The
// whole relay chain (kvq GEMM, relay attention, relay FFN, 2 BNs per layer)
// is eliminated. qkv+akav+akavr share weight panel Wj -> ONE stacked GEMM
// over A=[act(17408); embs(17408); relay0(1024)] = 35840 rows x 768.
// GEMM kernel = round-6 BK=128 structure (best measured: 41 us; rounds 4-9
// established this shape family is latency-floor-bound at ~41 us/dispatch
// per m102's small-shape curve — six structural variants all land 41-80 us).
// Row-major activations (row, channel), C=256 contiguous.
// ---------------------------------------------------------------------------

using bf16 = __hip_bfloat16;
typedef __attribute__((ext_vector_type(8))) short bf16x8v;
typedef __attribute__((ext_vector_type(4))) float f32x4;

namespace {
constexpr int kBT = 1024;
constexpr int kC = 256;
constexpr int kV = 17;
constexpr int kT = 256;
constexpr int kDIN = 1024;
constexpr int kRows = kBT * kV;                  // 17408
constexpr int kRowsS = kRows * 2 + kBT;          // 35840 stacked rows
constexpr float kInvSqrtDk = 0.17677669529663687f;
constexpr size_t SZ_BIG = (size_t)kRows * kC;
}  // namespace

__constant__ int c_nbi[17][5] = {
    {0, 1, 2, 5, 6},   {0, 1, 3, 0, 0},   {0, 2, 4, 0, 0},  {1, 3, 0, 0, 0},
    {2, 4, 0, 0, 0},   {0, 5, 7, 11, 0},  {0, 6, 8, 12, 0}, {5, 7, 9, 0, 0},
    {6, 8, 12, 0, 0},  {7, 9, 0, 0, 0},   {8, 10, 0, 0, 0}, {8, 11, 13, 0, 0},
    {10, 12, 14, 0, 0},{11, 13, 15, 0, 0},{12, 14, 16, 0, 0},
    {13, 15, 0, 0, 0}, {14, 16, 0, 0, 0}};
__constant__ int c_ncnt[17] = {5, 3, 3, 2, 2, 4, 4, 3, 3, 2, 2, 3, 3, 3, 3, 2, 2};

__device__ inline float bf2f(unsigned short s) {
  unsigned int u = ((unsigned int)s) << 16;
  float f;
  __builtin_memcpy(&f, &u, 4);
  return f;
}
__device__ inline unsigned short f2bf(float f) {
  unsigned int u;
  __builtin_memcpy(&u, &f, 4);
  unsigned int r = (u + 0x7fffu + ((u >> 16) & 1u)) >> 16;  // RNE
  return (unsigned short)r;
}
__device__ inline float4 ldbf4(const bf16* p) {
  ushort4 u = *(const ushort4*)p;
  return make_float4(bf2f(u.x), bf2f(u.y), bf2f(u.z), bf2f(u.w));
}
__device__ inline void stbf4(bf16* p, float4 v) {
  ushort4 u = make_ushort4(f2bf(v.x), f2bf(v.y), f2bf(v.z), f2bf(v.w));
  *(ushort4*)p = u;
}
__device__ inline float dot4(float4 a, float4 b) {
  return a.x * b.x + a.y * b.y + a.z * b.z + a.w * b.w;
}

__device__ inline void async16(const bf16* g, bf16* l) {
  __builtin_amdgcn_global_load_lds(
      (const __attribute__((address_space(1))) void*)g,
      (__attribute__((address_space(3))) void*)l, 16, 0, 0);
}

// ---- bf16 MFMA GEMM: C = A[M,K]@W[N,K]^T + bias (+res) ----
// flags: 1=relu, 2=fp32 out, 4=bf16 out
// Round-6 structure (best measured): BK=128 per barrier, 64 KB LDS,
// 16 async16/wave back-to-back, one drain, 4 sub-chunks x 16 MFMA.
__global__ __launch_bounds__(256) void k_mfma_gemm(
    const bf16* __restrict__ A, const bf16* __restrict__ W,
    const float* __restrict__ bias, const float* __restrict__ res,
    float* __restrict__ outF, bf16* __restrict__ outB,
    int M, int N, int K, int flags) {
  __shared__ bf16 As[128 * 128];   // 4 chunks x (128 x 32)
  __shared__ bf16 Bs[128 * 128];
  const int tid = threadIdx.x;
  const int wave = tid >> 6;
  const int lane = tid & 63;
  const int row0 = blockIdx.x * 128;
  const int col0 = blockIdx.y * 128;

  const int sub = lane >> 2;
  const int kq = (lane & 3) * 8;
  const int rg0 = (2 * wave + 0) * 16;
  const int rg1 = (2 * wave + 1) * 16;
  const bf16* ag0 = A + (size_t)(row0 + rg0 + sub) * K + kq;
  const bf16* ag1 = A + (size_t)(row0 + rg1 + sub) * K + kq;
  const bf16* bg0 = W + (size_t)(col0 + rg0 + sub) * K + kq;
  const bf16* bg1 = W + (size_t)(col0 + rg1 + sub) * K + kq;

  const int wm = wave >> 1, wn = wave & 1;
  const int fr = lane & 15;
  const int fk = (lane >> 4) * 8;

  f32x4 acc[4][4];
#pragma unroll
  for (int i = 0; i < 4; ++i)
#pragma unroll
    for (int j = 0; j < 4; ++j) acc[i][j] = (f32x4){0.f, 0.f, 0.f, 0.f};

  for (int k0 = 0; k0 < K; k0 += 128) {
    if (k0) __syncthreads();  // protect LDS from previous iteration's readers
#pragma unroll
    for (int kc = 0; kc < 4; ++kc) {
      const int off = k0 + kc * 32;
      async16(ag0 + off, &As[kc * 4096 + rg0 * 32]);
      async16(ag1 + off, &As[kc * 4096 + rg1 * 32]);
      async16(bg0 + off, &Bs[kc * 4096 + rg0 * 32]);
      async16(bg1 + off, &Bs[kc * 4096 + rg1 * 32]);
    }
    __syncthreads();  // drain: whole BK=128 panel resident
#pragma unroll
    for (int kc = 0; kc < 4; ++kc) {
      bf16x8v af[4], bfv[4];
#pragma unroll
      for (int i = 0; i < 4; ++i)
        af[i] =
            *(const bf16x8v*)&As[kc * 4096 + (wm * 64 + i * 16 + fr) * 32 + fk];
#pragma unroll
      for (int j = 0; j < 4; ++j)
        bfv[j] =
            *(const bf16x8v*)&Bs[kc * 4096 + (wn * 64 + j * 16 + fr) * 32 + fk];
#pragma unroll
      for (int i = 0; i < 4; ++i)
#pragma unroll
        for (int j = 0; j < 4; ++j)
          acc[i][j] = __builtin_amdgcn_mfma_f32_16x16x32_bf16(af[i], bfv[j],
                                                              acc[i][j], 0, 0,
                                                              0);
    }
  }

  const int crow = row0 + wm * 64;
  const int ccol = col0 + wn * 64;
#pragma unroll
  for (int j = 0; j < 4; ++j) {
    int col = ccol + j * 16 + fr;
    float bv = bias ? bias[col] : 0.f;
#pragma unroll
    for (int i = 0; i < 4; ++i) {
      int rowb = crow + i * 16 + (lane >> 4) * 4;
#pragma unroll
      for (int r = 0; r < 4; ++r) {
        size_t row = (size_t)(rowb + r);
        float v = acc[i][j][r] + bv;
        if (res) v += res[row * N + col];
        if (flags & 1) v = fmaxf(v, 0.f);
        if (flags & 2) outF[row * N + col] = v;
        if (flags & 4) outB[row * N + col] = __float2bfloat16(v);
      }
    }
  }
}

// data (B,C,V,T) -> nodes fp32 rows + embs bf16 rows
__global__ __launch_bounds__(256) void k_xform_in(const float* __restrict__ data,
                                                  float* __restrict__ nodes,
                                                  bf16* __restrict__ embs_bf) {
  __shared__ float tile[32][33];
  int ct = blockIdx.x * 32, tt = blockIdx.y * 32;
  int bv = blockIdx.z;
  int b = bv / kV, v = bv - b * kV;
  int tx = threadIdx.x & 31, ty = threadIdx.x >> 5;
  for (int i = ty; i < 32; i += 8)
    tile[i][tx] = data[(((size_t)b * kC + ct + i) * kV + v) * kT + tt + tx];
  __syncthreads();
  for (int i = ty; i < 32; i += 8) {
    size_t s = (size_t)b * kT + tt + i;
    size_t idx = (s * kV + v) * kC + ct + tx;
    float val = tile[tx][i];
    nodes[idx] = val;
    embs_bf[idx] = __float2bfloat16(val);
  }
}

__global__ __launch_bounds__(256) void k_xform_out(const float* __restrict__ nodes,
                                                   float* __restrict__ out) {
  __shared__ float tile[32][33];
  int ct = blockIdx.x * 32, tt = blockIdx.y * 32;
  int bv = blockIdx.z;
  int b = bv / kV, v = bv - b * kV;
  int tx = threadIdx.x & 31, ty = threadIdx.x >> 5;
  for (int i = ty; i < 32; i += 8) {
    size_t s = (size_t)b * kT + tt + i;
    tile[i][tx] = nodes[(s * kV + v) * kC + ct + tx];
  }
  __syncthreads();
  for (int i = ty; i < 32; i += 8)
    out[(((size_t)b * kC + ct + i) * kV + v) * kT + tt + tx] = tile[tx][i];
}

// relay0 init: mean over v of nodes -> bf16 only (relay branch is dead;
// only the initial relay feeds satellite attention via W@relay0)
__global__ __launch_bounds__(256) void k_relay_init(const float* __restrict__ nodes,
                                                    bf16* __restrict__ relay0_bf) {
  int t = threadIdx.x;
  int s = blockIdx.x * 4 + (t >> 6);
  int c4 = (t & 63) * 4;
  float4 acc = make_float4(0.f, 0.f, 0.f, 0.f);
#pragma unroll
  for (int v = 0; v < kV; ++v) {
    float4 x = *(const float4*)(nodes + ((size_t)s * kV + v) * kC + c4);
    acc.x += x.x; acc.y += x.y; acc.z += x.z; acc.w += x.w;
  }
  float4 r = make_float4(acc.x / 17.f, acc.y / 17.f, acc.z / 17.f, acc.w / 17.f);
  stbf4(relay0_bf + (size_t)s * kC + c4, r);
}

// layernorm: wave per row, float4; writes fp32 + bf16
__global__ __launch_bounds__(256) void k_layernorm(const float* __restrict__ X,
                                                   const float* __restrict__ g,
                                                   const float* __restrict__ b,
                                                   float* __restrict__ O,
                                                   bf16* __restrict__ Ob) {
  int t = threadIdx.x;
  int row = blockIdx.x * 4 + (t >> 6);
  int c4 = (t & 63) * 4;
  size_t i = (size_t)row * kC + c4;
  float4 x = *(const float4*)(X + i);
  float s = x.x + x.y + x.z + x.w;
  float q = dot4(x, x);
#pragma unroll
  for (int o = 32; o >= 1; o >>= 1) {
    s += __shfl_xor(s, o);
    q += __shfl_xor(q, o);
  }
  float m = s * (1.f / 256.f);
  float var = q * (1.f / 256.f) - m * m;
  float rs = rsqrtf(var + 1e-6f);
  float4 g4 = *(const float4*)(g + c4);
  float4 b4 = *(const float4*)(b + c4);
  float4 o4 = make_float4((x.x - m) * rs * g4.x + b4.x,
                          (x.y - m) * rs * g4.y + b4.y,
                          (x.z - m) * rs * g4.z + b4.z,
                          (x.w - m) * rs * g4.w + b4.w);
  *(float4*)(O + i) = o4;
  stbf4(Ob + i, o4);
}

// satellite attention, wave per (s,l). One stacked projection buffer P
// (stride 768): rows [0,17408) = nodes (q|k|v), rows [17408,34816) = embs
// (ak at +256, av at +512), rows [34816,35840) = relay0 (akr/avr likewise).
// z (fp32, stride 256) updated in place: z = z + att.
__global__ __launch_bounds__(256) void k_attn_sat(const bf16* __restrict__ P,
                                                  float* __restrict__ z) {
  int t = threadIdx.x;
  int rl = blockIdx.x * 4 + (t >> 6);
  int lane = t & 63;
  int s = rl / kV, l = rl - s * kV;
  int c4 = lane * 4;
  float4 q = ldbf4(P + (size_t)rl * 768 + c4);
  int cnt = c_ncnt[l];
  float sc[7];
  int nrow[5];
#pragma unroll
  for (int w = 0; w < 5; ++w) {
    nrow[w] = s * kV + c_nbi[l][w];
    float4 k = ldbf4(P + (size_t)nrow[w] * 768 + 256 + c4);
    float p = dot4(q, k);
    p += __shfl_xor(p, 1, 8);
    p += __shfl_xor(p, 2, 8);
    p += __shfl_xor(p, 4, 8);
    sc[w] = (w < cnt) ? p * kInvSqrtDk : -1e30f;
  }
  {
    float4 k = ldbf4(P + (size_t)(kRows + rl) * 768 + 256 + c4);
    float p = dot4(q, k);
    p += __shfl_xor(p, 1, 8);
    p += __shfl_xor(p, 2, 8);
    p += __shfl_xor(p, 4, 8);
    sc[5] = p * kInvSqrtDk;
  }
  {
    float4 k = ldbf4(P + (size_t)(2 * kRows + s) * 768 + 256 + c4);
    float p = dot4(q, k);
    p += __shfl_xor(p, 1, 8);
    p += __shfl_xor(p, 2, 8);
    p += __shfl_xor(p, 4, 8);
    sc[6] = p * kInvSqrtDk;
  }
  float mx = sc[0];
#pragma unroll
  for (int w = 1; w < 7; ++w) mx = fmaxf(mx, sc[w]);
  float den = 0.f;
#pragma unroll
  for (int w = 0; w < 7; ++w) {
    sc[w] = __expf(sc[w] - mx);
    den += sc[w];
  }
  float inv = 1.f / den;
  float4 acc = make_float4(0.f, 0.f, 0.f, 0.f);
#pragma unroll
  for (int w = 0; w < 5; ++w) {
    float4 v = ldbf4(P + (size_t)nrow[w] * 768 + 512 + c4);
    acc.x += sc[w] * v.x; acc.y += sc[w] * v.y;
    acc.z += sc[w] * v.z; acc.w += sc[w] * v.w;
  }
  {
    float4 v = ldbf4(P + (size_t)(kRows + rl) * 768 + 512 + c4);
    acc.x += sc[5] * v.x; acc.y += sc[5] * v.y;
    acc.z += sc[5] * v.z; acc.w += sc[5] * v.w;
  }
  {
    float4 v = ldbf4(P + (size_t)(2 * kRows + s) * 768 + 512 + c4);
    acc.x += sc[6] * v.x; acc.y += sc[6] * v.y;
    acc.z += sc[6] * v.z; acc.w += sc[6] * v.w;
  }
  size_t zi = (size_t)rl * kC + c4;
  float4 xv = *(const float4*)(z + zi);
  *(float4*)(z + zi) = make_float4(xv.x + acc.x * inv, xv.y + acc.y * inv,
                                   xv.z + acc.z * inv, xv.w + acc.w * inv);
}

// BN stage 1: 16 rows per block, scalar coalesced
__global__ __launch_bounds__(256) void k_bn_partial(const float* __restrict__ A,
                                                    float* __restrict__ part,
                                                    int nb) {
  int c = threadIdx.x, blk = blockIdx.x;
  int lo = blk * 16;
  float s = 0.f, q = 0.f;
#pragma unroll
  for (int r = 0; r < 16; ++r) {
    float v = A[(size_t)(lo + r) * kC + c];
    s += v;
    q += v * v;
  }
  part[(size_t)blk * kC + c] = s;
  part[(size_t)(nb + blk) * kC + c] = q;
}

// BN stage 2: block per channel; 256 threads strided over nb partials
__global__ __launch_bounds__(256) void k_bn_finalize(const float* __restrict__ part,
                                                     int nb, float inv_n,
                                                     const float* __restrict__ g,
                                                     const float* __restrict__ b,
                                                     float* __restrict__ scale,
                                                     float* __restrict__ shift) {
  int c = blockIdx.x;
  int t = threadIdx.x;
  float s = 0.f, q = 0.f;
  for (int i = t; i < nb; i += 256) {
    s += part[(size_t)i * kC + c];
    q += part[(size_t)(nb + i) * kC + c];
  }
#pragma unroll
  for (int o = 32; o >= 1; o >>= 1) {
    s += __shfl_xor(s, o);
    q += __shfl_xor(q, o);
  }
  __shared__ float ws[4], wq[4];
  int wid = t >> 6;
  if ((t & 63) == 0) { ws[wid] = s; wq[wid] = q; }
  __syncthreads();
  if (t == 0) {
    float S = ws[0] + ws[1] + ws[2] + ws[3];
    float Q = wq[0] + wq[1] + wq[2] + wq[3];
    float m = S * inv_n;
    float var = Q * inv_n - m * m;
    float sc = g[c] * rsqrtf(var + 1e-5f);
    scale[c] = sc;
    shift[c] = b[c] - m * sc;
  }
}

// BN stage 3: 4 rows/block, float4; writes fp32 and/or bf16
__global__ __launch_bounds__(256) void k_bn_apply(const float* __restrict__ Z,
                                                  const float* __restrict__ scale,
                                                  const float* __restrict__ shift,
                                                  float* __restrict__ outF,
                                                  bf16* __restrict__ outB,
                                                  int leaky) {
  int t = threadIdx.x;
  int row = blockIdx.x * 4 + (t >> 6);
  int c4 = (t & 63) * 4;
  size_t i = (size_t)row * kC + c4;
  float4 z = *(const float4*)(Z + i);
  float4 sc = *(const float4*)(scale + c4);
  float4 sh = *(const float4*)(shift + c4);
  float4 v = make_float4(z.x * sc.x + sh.x, z.y * sc.y + sh.y,
                         z.z * sc.z + sh.z, z.w * sc.w + sh.w);
  if (leaky) {
    v.x = (v.x > 0.f) ? v.x : 0.01f * v.x;
    v.y = (v.y > 0.f) ? v.y : 0.01f * v.y;
    v.z = (v.z > 0.f) ? v.z : 0.01f * v.z;
    v.w = (v.w > 0.f) ? v.w : 0.01f * v.w;
  }
  if (outF) *(float4*)(outF + i) = v;
  if (outB) stbf4(outB + i, v);
}

// batched f32->bf16 conversion (8 chunks, one launch)
struct CvtTab {
  const float* src[8];
  bf16* dst[8];
  int n[8];
};
__global__ __launch_bounds__(256) void k_cvt_multi(CvtTab t) {
  int c = blockIdx.y;
  int i = (blockIdx.x * 256 + threadIdx.x) * 4;
  if (i >= t.n[c]) return;
  float4 v = *(const float4*)(t.src[c] + i);
  stbf4(t.dst[c] + i, v);
}

// batched bias copies (6 segments of 256)
struct BiasTab {
  const float* src[6];
  float* dst[6];
};
__global__ __launch_bounds__(256) void k_bias_cat(BiasTab t) {
  t.dst[blockIdx.x][threadIdx.x] = t.src[blockIdx.x][threadIdx.x];
}

extern "C" void kernel_launch(void* const* d_in, const int* in_sizes, int n_in,
                              void* d_out, int out_size, void* d_ws, size_t ws_size,
                              hipStream_t stream) {
  const float* data = (const float*)d_in[0];
  const float* ln_g = (const float*)d_in[1];
  const float* ln_b = (const float*)d_in[2];
  const float* jq_w = (const float*)d_in[3];
  const float* jq_b = (const float*)d_in[4];
  const float* jk_w = (const float*)d_in[5];
  const float* jk_b = (const float*)d_in[6];
  const float* jv_w = (const float*)d_in[7];
  const float* jv_b = (const float*)d_in[8];
  const float* jbn_g = (const float*)d_in[9];
  const float* jbn_b = (const float*)d_in[10];
  const float* jf1_w = (const float*)d_in[11];
  const float* jf1_b = (const float*)d_in[12];
  const float* jf2_w = (const float*)d_in[13];
  const float* jf2_b = (const float*)d_in[14];
  const float* jfbn_g = (const float*)d_in[15];
  const float* jfbn_b = (const float*)d_in[16];
  // d_in[17..30]: relay-branch weights — dead code, unused.
  float* out = (float*)d_out;

  // ---- arena ----
  float* f = (float*)d_ws;
  float* nodes = f;    f += SZ_BIG;           // pre-LN nodes; 'ret' mid-layer
  float* xn = f;       f += SZ_BIG;           // LN out -> z -> y2
  float* part = f;     f += 2 * 1088 * kC;
  float* scale = f;    f += kC;
  float* shift = f;    f += kC;
  float* cb_jqkv = f;  f += 2 * 768;

  bf16* bfa = (bf16*)f;
  bf16* stackA = bfa;  bfa += (size_t)kRowsS * kC;  // [act | embs | relay0]
  bf16* P = bfa;       bfa += (size_t)kRowsS * 768; // stacked proj; h_bf alias
  bf16* Wjqkv = bfa;   bfa += 2 * 768 * 256;
  bf16* Wjf1 = bfa;    bfa += 2 * 1024 * 256;
  bf16* Wjf2 = bfa;    bfa += 2 * 256 * 1024;

  bf16* act_bf = stackA;                       // rows [0, 17408)
  bf16* embs_bf = stackA + SZ_BIG;             // rows [17408, 34816)
  bf16* relay0_bf = stackA + 2 * SZ_BIG;       // rows [34816, 35840)
  bf16* h_bf = P;                              // 17408 x 1024 fits in P
  float* y2 = xn;

  auto gemm = [&](const bf16* A, const bf16* W, const float* bias,
                  const float* res, float* oF, bf16* oB, int M, int N, int K,
                  int flags) {
    dim3 g(M / 128, N / 128);
    k_mfma_gemm<<<g, 256, 0, stream>>>(A, W, bias, res, oF, oB, M, N, K, flags);
  };
  auto bn = [&](const float* Z, int rows, const float* g_, const float* b_,
                float* dstF, bf16* dstB, int leaky) {
    int nb = rows / 16;
    k_bn_partial<<<nb, 256, 0, stream>>>(Z, part, nb);
    k_bn_finalize<<<kC, 256, 0, stream>>>(part, nb, 1.f / rows, g_, b_, scale,
                                          shift);
    k_bn_apply<<<rows / 4, 256, 0, stream>>>(Z, scale, shift, dstF, dstB, leaky);
  };

  // ---- weight conversion (one launch) ----
  {
    CvtTab t;
    for (int i = 0; i < 2; ++i) {
      const size_t om = (size_t)i * kC * kC;
      const float* s3[3] = {jq_w + om, jk_w + om, jv_w + om};
      bf16* d3[3] = {Wjqkv + (size_t)i * 768 * 256,
                     Wjqkv + (size_t)i * 768 * 256 + 65536,
                     Wjqkv + (size_t)i * 768 * 256 + 131072};
      for (int j = 0; j < 3; ++j) {
        t.src[i * 3 + j] = s3[j];
        t.dst[i * 3 + j] = d3[j];
        t.n[i * 3 + j] = 65536;
      }
    }
    t.src[6] = jf1_w; t.dst[6] = Wjf1; t.n[6] = 2 * 1024 * 256;
    t.src[7] = jf2_w; t.dst[7] = Wjf2; t.n[7] = 2 * 256 * 1024;
    k_cvt_multi<<<dim3(512, 8), 256, 0, stream>>>(t);
  }
  {
    BiasTab t;
    for (int i = 0; i < 2; ++i) {
      t.src[i * 3 + 0] = jq_b + (size_t)i * kC;
      t.src[i * 3 + 1] = jk_b + (size_t)i * kC;
      t.src[i * 3 + 2] = jv_b + (size_t)i * kC;
      t.dst[i * 3 + 0] = cb_jqkv + i * 768;
      t.dst[i * 3 + 1] = cb_jqkv + i * 768 + 256;
      t.dst[i * 3 + 2] = cb_jqkv + i * 768 + 512;
    }
    k_bias_cat<<<6, 256, 0, stream>>>(t);
  }

  k_xform_in<<<dim3(8, 8, 4 * kV), 256, 0, stream>>>(data, nodes, embs_bf);
  k_relay_init<<<kBT / 4, 256, 0, stream>>>(nodes, relay0_bf);

  for (int i = 0; i < 2; ++i) {
    const size_t ob = (size_t)i * kC, ofb1 = (size_t)i * kDIN;
    const bf16* Wj = Wjqkv + (size_t)i * 768 * 256;
    const bf16* Wf1 = Wjf1 + (size_t)i * 1024 * 256;
    const bf16* Wf2 = Wjf2 + (size_t)i * 256 * 1024;
    const float* cbj = cb_jqkv + i * 768;

    // LN writes act_bf (stacked rows 0..17407); embs/relay0 rows are fixed.
    k_layernorm<<<kRows / 4, 256, 0, stream>>>(nodes, ln_g + ob, ln_b + ob, xn,
                                               act_bf);
    // ONE stacked projection: [act;embs;relay0] (35840) x Wj(768x256)^T.
    // q-cols of embs/relay0 rows are wasted but merge 3 dispatches into 1.
    gemm(stackA, Wj, cbj, nullptr, nullptr, P, kRowsS, 768, 256, 4);
    k_attn_sat<<<kRows / 4, 256, 0, stream>>>(P, xn);  // z = xn + att
    bn(xn, kRows, jbn_g + ob, jbn_b + ob, nodes, act_bf, 0);  // ret
    gemm(act_bf, Wf1, jf1_b + ofb1, nullptr, nullptr, h_bf, kRows, 1024, 256,
         4 | 1);
    gemm(h_bf, Wf2, jf2_b + ob, nodes, y2, nullptr, kRows, 256, 1024, 2);
    bn(y2, kRows, jfbn_g + ob, jfbn_b + ob, nodes, nullptr, 1);
  }

  k_xform_out<<<dim3(8, 8, 4 * kV), 256, 0, stream>>>(nodes, out);
  (void)in_sizes; (void)n_in; (void)out_size; (void)ws_size;
}

// Round 11
// 441.367 us; speedup vs baseline: 2.0323x; 1.1057x over previous
//
#include <hip/hip_runtime.h>
#include <hip/hip_bf16.h>

// ---------------------------------------------------------------------------
// Star-Transformer 2-layer forward — satellite branch only (relay chain is
// dead code for the output, established round 10).
// Round 11: (1) GEMM bf16 epilogue repacks C through LDS -> full-sector 16B
// coalesced stores (round-10 WRITE_SIZE showed ~1.6x write amplification on
// scalar 2B stores); (2) embs/relay0 K/V projections for BOTH layers hoisted
// into one pre-loop GEMM ([embs;relay0] x [k0|v0|k1|v1]) — they're fixed
// across layers; per-layer proj = act x (q|k|v) only; (3) BN2-apply fused
// with next-layer LN at the layer boundary.
// GEMM core = round-6 BK=128 structure (best measured across 6 variants).
// Row-major activations (row, channel), C=256 contiguous.
// ---------------------------------------------------------------------------

using bf16 = __hip_bfloat16;
typedef __attribute__((ext_vector_type(8))) short bf16x8v;
typedef __attribute__((ext_vector_type(4))) float f32x4;

namespace {
constexpr int kBT = 1024;
constexpr int kC = 256;
constexpr int kV = 17;
constexpr int kT = 256;
constexpr int kDIN = 1024;
constexpr int kRows = kBT * kV;                  // 17408
constexpr int kRowsE = kRows + kBT;              // 18432 = embs + relay0
constexpr float kInvSqrtDk = 0.17677669529663687f;
constexpr size_t SZ_BIG = (size_t)kRows * kC;
}  // namespace

__constant__ int c_nbi[17][5] = {
    {0, 1, 2, 5, 6},   {0, 1, 3, 0, 0},   {0, 2, 4, 0, 0},  {1, 3, 0, 0, 0},
    {2, 4, 0, 0, 0},   {0, 5, 7, 11, 0},  {0, 6, 8, 12, 0}, {5, 7, 9, 0, 0},
    {6, 8, 12, 0, 0},  {7, 9, 0, 0, 0},   {8, 10, 0, 0, 0}, {8, 11, 13, 0, 0},
    {10, 12, 14, 0, 0},{11, 13, 15, 0, 0},{12, 14, 16, 0, 0},
    {13, 15, 0, 0, 0}, {14, 16, 0, 0, 0}};
__constant__ int c_ncnt[17] = {5, 3, 3, 2, 2, 4, 4, 3, 3, 2, 2, 3, 3, 3, 3, 2, 2};

__device__ inline float bf2f(unsigned short s) {
  unsigned int u = ((unsigned int)s) << 16;
  float f;
  __builtin_memcpy(&f, &u, 4);
  return f;
}
__device__ inline unsigned short f2bf(float f) {
  unsigned int u;
  __builtin_memcpy(&u, &f, 4);
  unsigned int r = (u + 0x7fffu + ((u >> 16) & 1u)) >> 16;  // RNE
  return (unsigned short)r;
}
__device__ inline float4 ldbf4(const bf16* p) {
  ushort4 u = *(const ushort4*)p;
  return make_float4(bf2f(u.x), bf2f(u.y), bf2f(u.z), bf2f(u.w));
}
__device__ inline void stbf4(bf16* p, float4 v) {
  ushort4 u = make_ushort4(f2bf(v.x), f2bf(v.y), f2bf(v.z), f2bf(v.w));
  *(ushort4*)p = u;
}
__device__ inline float dot4(float4 a, float4 b) {
  return a.x * b.x + a.y * b.y + a.z * b.z + a.w * b.w;
}

__device__ inline void async16(const bf16* g, bf16* l) {
  __builtin_amdgcn_global_load_lds(
      (const __attribute__((address_space(1))) void*)g,
      (__attribute__((address_space(3))) void*)l, 16, 0, 0);
}

// ---- bf16 MFMA GEMM: C = A[M,K]@W[N,K]^T + bias (+res) ----
// flags: 1=relu, 2=fp32 out (direct, 64B-sector stores), 4=bf16 out
// (repacked through LDS -> 16B/lane full-sector stores).
__global__ __launch_bounds__(256) void k_mfma_gemm(
    const bf16* __restrict__ A, const bf16* __restrict__ W,
    const float* __restrict__ bias, const float* __restrict__ res,
    float* __restrict__ outF, bf16* __restrict__ outB,
    int M, int N, int K, int flags) {
  __shared__ bf16 As[128 * 128];   // 4 chunks x (128 x 32); epilogue C-stage
  __shared__ bf16 Bs[128 * 128];
  const int tid = threadIdx.x;
  const int wave = tid >> 6;
  const int lane = tid & 63;
  const int row0 = blockIdx.x * 128;
  const int col0 = blockIdx.y * 128;

  const int sub = lane >> 2;
  const int kq = (lane & 3) * 8;
  const int rg0 = (2 * wave + 0) * 16;
  const int rg1 = (2 * wave + 1) * 16;
  const bf16* ag0 = A + (size_t)(row0 + rg0 + sub) * K + kq;
  const bf16* ag1 = A + (size_t)(row0 + rg1 + sub) * K + kq;
  const bf16* bg0 = W + (size_t)(col0 + rg0 + sub) * K + kq;
  const bf16* bg1 = W + (size_t)(col0 + rg1 + sub) * K + kq;

  const int wm = wave >> 1, wn = wave & 1;
  const int fr = lane & 15;
  const int fk = (lane >> 4) * 8;

  f32x4 acc[4][4];
#pragma unroll
  for (int i = 0; i < 4; ++i)
#pragma unroll
    for (int j = 0; j < 4; ++j) acc[i][j] = (f32x4){0.f, 0.f, 0.f, 0.f};

  for (int k0 = 0; k0 < K; k0 += 128) {
    if (k0) __syncthreads();
#pragma unroll
    for (int kc = 0; kc < 4; ++kc) {
      const int off = k0 + kc * 32;
      async16(ag0 + off, &As[kc * 4096 + rg0 * 32]);
      async16(ag1 + off, &As[kc * 4096 + rg1 * 32]);
      async16(bg0 + off, &Bs[kc * 4096 + rg0 * 32]);
      async16(bg1 + off, &Bs[kc * 4096 + rg1 * 32]);
    }
    __syncthreads();
#pragma unroll
    for (int kc = 0; kc < 4; ++kc) {
      bf16x8v af[4], bfv[4];
#pragma unroll
      for (int i = 0; i < 4; ++i)
        af[i] =
            *(const bf16x8v*)&As[kc * 4096 + (wm * 64 + i * 16 + fr) * 32 + fk];
#pragma unroll
      for (int j = 0; j < 4; ++j)
        bfv[j] =
            *(const bf16x8v*)&Bs[kc * 4096 + (wn * 64 + j * 16 + fr) * 32 + fk];
#pragma unroll
      for (int i = 0; i < 4; ++i)
#pragma unroll
        for (int j = 0; j < 4; ++j)
          acc[i][j] = __builtin_amdgcn_mfma_f32_16x16x32_bf16(af[i], bfv[j],
                                                              acc[i][j], 0, 0,
                                                              0);
    }
  }

  if (flags & 4) {
    // bf16 out: stage C-tile in LDS (ushort 128x128 = 32 KB in As), then
    // 8 passes of 16 rows x 256B fully-coalesced stores.
    unsigned short* cs = (unsigned short*)As;
    __syncthreads();  // all waves done reading As/Bs
#pragma unroll
    for (int j = 0; j < 4; ++j) {
      int lc = wn * 64 + j * 16 + fr;
      float bv = bias ? bias[col0 + lc] : 0.f;
#pragma unroll
      for (int i = 0; i < 4; ++i) {
        int lr = wm * 64 + i * 16 + (lane >> 4) * 4;
#pragma unroll
        for (int r = 0; r < 4; ++r) {
          float v = acc[i][j][r] + bv;
          if (flags & 1) v = fmaxf(v, 0.f);
          cs[(lr + r) * 128 + lc] = f2bf(v);
        }
      }
    }
    __syncthreads();
#pragma unroll
    for (int p = 0; p < 8; ++p) {
      int lr = p * 16 + (tid >> 4);
      int lc = (tid & 15) * 8;
      *(bf16x8v*)&outB[(size_t)(row0 + lr) * N + col0 + lc] =
          *(const bf16x8v*)&cs[lr * 128 + lc];
    }
  } else {
    // fp32 out: 16 lanes x 4B = full 64B sectors, store direct.
    const int crow = row0 + wm * 64;
    const int ccol = col0 + wn * 64;
#pragma unroll
    for (int j = 0; j < 4; ++j) {
      int col = ccol + j * 16 + fr;
      float bv = bias ? bias[col] : 0.f;
#pragma unroll
      for (int i = 0; i < 4; ++i) {
        int rowb = crow + i * 16 + (lane >> 4) * 4;
#pragma unroll
        for (int r = 0; r < 4; ++r) {
          size_t row = (size_t)(rowb + r);
          float v = acc[i][j][r] + bv;
          if (res) v += res[row * N + col];
          if (flags & 1) v = fmaxf(v, 0.f);
          outF[row * N + col] = v;
        }
      }
    }
  }
}

// data (B,C,V,T) -> nodes fp32 rows + embs bf16 rows
__global__ __launch_bounds__(256) void k_xform_in(const float* __restrict__ data,
                                                  float* __restrict__ nodes,
                                                  bf16* __restrict__ embs_bf) {
  __shared__ float tile[32][33];
  int ct = blockIdx.x * 32, tt = blockIdx.y * 32;
  int bv = blockIdx.z;
  int b = bv / kV, v = bv - b * kV;
  int tx = threadIdx.x & 31, ty = threadIdx.x >> 5;
  for (int i = ty; i < 32; i += 8)
    tile[i][tx] = data[(((size_t)b * kC + ct + i) * kV + v) * kT + tt + tx];
  __syncthreads();
  for (int i = ty; i < 32; i += 8) {
    size_t s = (size_t)b * kT + tt + i;
    size_t idx = (s * kV + v) * kC + ct + tx;
    float val = tile[tx][i];
    nodes[idx] = val;
    embs_bf[idx] = __float2bfloat16(val);
  }
}

__global__ __launch_bounds__(256) void k_xform_out(const float* __restrict__ nodes,
                                                   float* __restrict__ out) {
  __shared__ float tile[32][33];
  int ct = blockIdx.x * 32, tt = blockIdx.y * 32;
  int bv = blockIdx.z;
  int b = bv / kV, v = bv - b * kV;
  int tx = threadIdx.x & 31, ty = threadIdx.x >> 5;
  for (int i = ty; i < 32; i += 8) {
    size_t s = (size_t)b * kT + tt + i;
    tile[i][tx] = nodes[(s * kV + v) * kC + ct + tx];
  }
  __syncthreads();
  for (int i = ty; i < 32; i += 8)
    out[(((size_t)b * kC + ct + i) * kV + v) * kT + tt + tx] = tile[tx][i];
}

// relay0 init: mean over v of nodes -> bf16 (rows kRows..kRowsE-1 of embsX)
__global__ __launch_bounds__(256) void k_relay_init(const float* __restrict__ nodes,
                                                    bf16* __restrict__ relay0_bf) {
  int t = threadIdx.x;
  int s = blockIdx.x * 4 + (t >> 6);
  int c4 = (t & 63) * 4;
  float4 acc = make_float4(0.f, 0.f, 0.f, 0.f);
#pragma unroll
  for (int v = 0; v < kV; ++v) {
    float4 x = *(const float4*)(nodes + ((size_t)s * kV + v) * kC + c4);
    acc.x += x.x; acc.y += x.y; acc.z += x.z; acc.w += x.w;
  }
  float4 r = make_float4(acc.x / 17.f, acc.y / 17.f, acc.z / 17.f, acc.w / 17.f);
  stbf4(relay0_bf + (size_t)s * kC + c4, r);
}

// layernorm: wave per row, float4; writes fp32 + bf16
__global__ __launch_bounds__(256) void k_layernorm(const float* __restrict__ X,
                                                   const float* __restrict__ g,
                                                   const float* __restrict__ b,
                                                   float* __restrict__ O,
                                                   bf16* __restrict__ Ob) {
  int t = threadIdx.x;
  int row = blockIdx.x * 4 + (t >> 6);
  int c4 = (t & 63) * 4;
  size_t i = (size_t)row * kC + c4;
  float4 x = *(const float4*)(X + i);
  float s = x.x + x.y + x.z + x.w;
  float q = dot4(x, x);
#pragma unroll
  for (int o = 32; o >= 1; o >>= 1) {
    s += __shfl_xor(s, o);
    q += __shfl_xor(q, o);
  }
  float m = s * (1.f / 256.f);
  float var = q * (1.f / 256.f) - m * m;
  float rs = rsqrtf(var + 1e-6f);
  float4 g4 = *(const float4*)(g + c4);
  float4 b4 = *(const float4*)(b + c4);
  float4 o4 = make_float4((x.x - m) * rs * g4.x + b4.x,
                          (x.y - m) * rs * g4.y + b4.y,
                          (x.z - m) * rs * g4.z + b4.z,
                          (x.w - m) * rs * g4.w + b4.w);
  *(float4*)(O + i) = o4;
  stbf4(Ob + i, o4);
}

// satellite attention, wave per (s,l).
// qkv: 17408 x 768 bf16 [q|k|v] for nodes. akav: stride 1024, caller passes
// base + layer*512; cols +0 = k, +256 = v; rows rl = embs, kRows+s = relay0.
// z (fp32, stride 256) updated in place: z = z + att.
__global__ __launch_bounds__(256) void k_attn_sat(const bf16* __restrict__ qkv,
                                                  const bf16* __restrict__ akav,
                                                  float* __restrict__ z) {
  int t = threadIdx.x;
  int rl = blockIdx.x * 4 + (t >> 6);
  int lane = t & 63;
  int s = rl / kV, l = rl - s * kV;
  int c4 = lane * 4;
  float4 q = ldbf4(qkv + (size_t)rl * 768 + c4);
  int cnt = c_ncnt[l];
  float sc[7];
  int nrow[5];
#pragma unroll
  for (int w = 0; w < 5; ++w) {
    nrow[w] = s * kV + c_nbi[l][w];
    float4 k = ldbf4(qkv + (size_t)nrow[w] * 768 + 256 + c4);
    float p = dot4(q, k);
    p += __shfl_xor(p, 1, 8);
    p += __shfl_xor(p, 2, 8);
    p += __shfl_xor(p, 4, 8);
    sc[w] = (w < cnt) ? p * kInvSqrtDk : -1e30f;
  }
  {
    float4 k = ldbf4(akav + (size_t)rl * 1024 + c4);
    float p = dot4(q, k);
    p += __shfl_xor(p, 1, 8);
    p += __shfl_xor(p, 2, 8);
    p += __shfl_xor(p, 4, 8);
    sc[5] = p * kInvSqrtDk;
  }
  {
    float4 k = ldbf4(akav + (size_t)(kRows + s) * 1024 + c4);
    float p = dot4(q, k);
    p += __shfl_xor(p, 1, 8);
    p += __shfl_xor(p, 2, 8);
    p += __shfl_xor(p, 4, 8);
    sc[6] = p * kInvSqrtDk;
  }
  float mx = sc[0];
#pragma unroll
  for (int w = 1; w < 7; ++w) mx = fmaxf(mx, sc[w]);
  float den = 0.f;
#pragma unroll
  for (int w = 0; w < 7; ++w) {
    sc[w] = __expf(sc[w] - mx);
    den += sc[w];
  }
  float inv = 1.f / den;
  float4 acc = make_float4(0.f, 0.f, 0.f, 0.f);
#pragma unroll
  for (int w = 0; w < 5; ++w) {
    float4 v = ldbf4(qkv + (size_t)nrow[w] * 768 + 512 + c4);
    acc.x += sc[w] * v.x; acc.y += sc[w] * v.y;
    acc.z += sc[w] * v.z; acc.w += sc[w] * v.w;
  }
  {
    float4 v = ldbf4(akav + (size_t)rl * 1024 + 256 + c4);
    acc.x += sc[5] * v.x; acc.y += sc[5] * v.y;
    acc.z += sc[5] * v.z; acc.w += sc[5] * v.w;
  }
  {
    float4 v = ldbf4(akav + (size_t)(kRows + s) * 1024 + 256 + c4);
    acc.x += sc[6] * v.x; acc.y += sc[6] * v.y;
    acc.z += sc[6] * v.z; acc.w += sc[6] * v.w;
  }
  size_t zi = (size_t)rl * kC + c4;
  float4 xv = *(const float4*)(z + zi);
  *(float4*)(z + zi) = make_float4(xv.x + acc.x * inv, xv.y + acc.y * inv,
                                   xv.z + acc.z * inv, xv.w + acc.w * inv);
}

// BN stage 1: 16 rows per block, scalar coalesced
__global__ __launch_bounds__(256) void k_bn_partial(const float* __restrict__ A,
                                                    float* __restrict__ part,
                                                    int nb) {
  int c = threadIdx.x, blk = blockIdx.x;
  int lo = blk * 16;
  float s = 0.f, q = 0.f;
#pragma unroll
  for (int r = 0; r < 16; ++r) {
    float v = A[(size_t)(lo + r) * kC + c];
    s += v;
    q += v * v;
  }
  part[(size_t)blk * kC + c] = s;
  part[(size_t)(nb + blk) * kC + c] = q;
}

// BN stage 2: block per channel
__global__ __launch_bounds__(256) void k_bn_finalize(const float* __restrict__ part,
                                                     int nb, float inv_n,
                                                     const float* __restrict__ g,
                                                     const float* __restrict__ b,
                                                     float* __restrict__ scale,
                                                     float* __restrict__ shift) {
  int c = blockIdx.x;
  int t = threadIdx.x;
  float s = 0.f, q = 0.f;
  for (int i = t; i < nb; i += 256) {
    s += part[(size_t)i * kC + c];
    q += part[(size_t)(nb + i) * kC + c];
  }
#pragma unroll
  for (int o = 32; o >= 1; o >>= 1) {
    s += __shfl_xor(s, o);
    q += __shfl_xor(q, o);
  }
  __shared__ float ws[4], wq[4];
  int wid = t >> 6;
  if ((t & 63) == 0) { ws[wid] = s; wq[wid] = q; }
  __syncthreads();
  if (t == 0) {
    float S = ws[0] + ws[1] + ws[2] + ws[3];
    float Q = wq[0] + wq[1] + wq[2] + wq[3];
    float m = S * inv_n;
    float var = Q * inv_n - m * m;
    float sc = g[c] * rsqrtf(var + 1e-5f);
    scale[c] = sc;
    shift[c] = b[c] - m * sc;
  }
}

// BN stage 3: 4 rows/block, float4; writes fp32 and/or bf16
__global__ __launch_bounds__(256) void k_bn_apply(const float* __restrict__ Z,
                                                  const float* __restrict__ scale,
                                                  const float* __restrict__ shift,
                                                  float* __restrict__ outF,
                                                  bf16* __restrict__ outB,
                                                  int leaky) {
  int t = threadIdx.x;
  int row = blockIdx.x * 4 + (t >> 6);
  int c4 = (t & 63) * 4;
  size_t i = (size_t)row * kC + c4;
  float4 z = *(const float4*)(Z + i);
  float4 sc = *(const float4*)(scale + c4);
  float4 sh = *(const float4*)(shift + c4);
  float4 v = make_float4(z.x * sc.x + sh.x, z.y * sc.y + sh.y,
                         z.z * sc.z + sh.z, z.w * sc.w + sh.w);
  if (leaky) {
    v.x = (v.x > 0.f) ? v.x : 0.01f * v.x;
    v.y = (v.y > 0.f) ? v.y : 0.01f * v.y;
    v.z = (v.z > 0.f) ? v.z : 0.01f * v.z;
    v.w = (v.w > 0.f) ? v.w : 0.01f * v.w;
  }
  if (outF) *(float4*)(outF + i) = v;
  if (outB) stbf4(outB + i, v);
}

// Fused BN2(leaky)+LN at the layer boundary: one read of Z, writes
// nodes (post-BN), xn (LN out fp32; may alias Z — each elem read before
// written by its own thread) and act_bf (LN out bf16).
__global__ __launch_bounds__(256) void k_bn_ln(
    const float* __restrict__ Z, const float* __restrict__ scale,
    const float* __restrict__ shift, const float* __restrict__ g,
    const float* __restrict__ b, float* __restrict__ nodesOut,
    float* __restrict__ xnOut, bf16* __restrict__ actOut) {
  int t = threadIdx.x;
  int row = blockIdx.x * 4 + (t >> 6);
  int c4 = (t & 63) * 4;
  size_t i = (size_t)row * kC + c4;
  float4 z = *(const float4*)(Z + i);
  float4 sc = *(const float4*)(scale + c4);
  float4 sh = *(const float4*)(shift + c4);
  float4 v = make_float4(z.x * sc.x + sh.x, z.y * sc.y + sh.y,
                         z.z * sc.z + sh.z, z.w * sc.w + sh.w);
  v.x = (v.x > 0.f) ? v.x : 0.01f * v.x;
  v.y = (v.y > 0.f) ? v.y : 0.01f * v.y;
  v.z = (v.z > 0.f) ? v.z : 0.01f * v.z;
  v.w = (v.w > 0.f) ? v.w : 0.01f * v.w;
  *(float4*)(nodesOut + i) = v;
  float s = v.x + v.y + v.z + v.w;
  float q = dot4(v, v);
#pragma unroll
  for (int o = 32; o >= 1; o >>= 1) {
    s += __shfl_xor(s, o);
    q += __shfl_xor(q, o);
  }
  float m = s * (1.f / 256.f);
  float var = q * (1.f / 256.f) - m * m;
  float rs = rsqrtf(var + 1e-6f);
  float4 g4 = *(const float4*)(g + c4);
  float4 b4 = *(const float4*)(b + c4);
  float4 o4 = make_float4((v.x - m) * rs * g4.x + b4.x,
                          (v.y - m) * rs * g4.y + b4.y,
                          (v.z - m) * rs * g4.z + b4.z,
                          (v.w - m) * rs * g4.w + b4.w);
  *(float4*)(xnOut + i) = o4;
  stbf4(actOut + i, o4);
}

// batched f32->bf16 conversion (12 chunks, one launch)
struct CvtTab {
  const float* src[12];
  bf16* dst[12];
  int n[12];
};
__global__ __launch_bounds__(256) void k_cvt_multi(CvtTab t) {
  int c = blockIdx.y;
  int i = (blockIdx.x * 256 + threadIdx.x) * 4;
  if (i >= t.n[c]) return;
  float4 v = *(const float4*)(t.src[c] + i);
  stbf4(t.dst[c] + i, v);
}

// batched bias copies (10 segments of 256)
struct BiasTab {
  const float* src[10];
  float* dst[10];
};
__global__ __launch_bounds__(256) void k_bias_cat(BiasTab t) {
  t.dst[blockIdx.x][threadIdx.x] = t.src[blockIdx.x][threadIdx.x];
}

extern "C" void kernel_launch(void* const* d_in, const int* in_sizes, int n_in,
                              void* d_out, int out_size, void* d_ws, size_t ws_size,
                              hipStream_t stream) {
  const float* data = (const float*)d_in[0];
  const float* ln_g = (const float*)d_in[1];
  const float* ln_b = (const float*)d_in[2];
  const float* jq_w = (const float*)d_in[3];
  const float* jq_b = (const float*)d_in[4];
  const float* jk_w = (const float*)d_in[5];
  const float* jk_b = (const float*)d_in[6];
  const float* jv_w = (const float*)d_in[7];
  const float* jv_b = (const float*)d_in[8];
  const float* jbn_g = (const float*)d_in[9];
  const float* jbn_b = (const float*)d_in[10];
  const float* jf1_w = (const float*)d_in[11];
  const float* jf1_b = (const float*)d_in[12];
  const float* jf2_w = (const float*)d_in[13];
  const float* jf2_b = (const float*)d_in[14];
  const float* jfbn_g = (const float*)d_in[15];
  const float* jfbn_b = (const float*)d_in[16];
  // d_in[17..30]: relay-branch weights — dead code, unused.
  float* out = (float*)d_out;

  // ---- arena ----
  float* f = (float*)d_ws;
  float* nodes = f;    f += SZ_BIG;
  float* xn = f;       f += SZ_BIG;           // LN out -> z -> y2
  float* part = f;     f += 2 * 1088 * kC;
  float* scale = f;    f += kC;
  float* shift = f;    f += kC;
  float* cb_jqkv = f;  f += 2 * 768;
  float* cb_kv4 = f;   f += 1024;

  bf16* bfa = (bf16*)f;
  bf16* act_bf = bfa;   bfa += SZ_BIG;                 // 17408 x 256
  bf16* embsX_bf = bfa; bfa += (size_t)kRowsE * kC;    // [embs; relay0]
  bf16* P = bfa;        bfa += (size_t)kRows * kDIN;   // qkv (768) / h (1024)
  bf16* akavBuf = bfa;  bfa += (size_t)kRowsE * 1024;  // [k0|v0|k1|v1]
  bf16* Wjqkv = bfa;    bfa += 2 * 768 * 256;
  bf16* Wkv4 = bfa;     bfa += 1024 * 256;
  bf16* Wjf1 = bfa;     bfa += 2 * 1024 * 256;
  bf16* Wjf2 = bfa;     bfa += 2 * 256 * 1024;

  bf16* relay0_bf = embsX_bf + SZ_BIG;  // rows kRows..kRowsE-1
  bf16* qkv_bf = P;                     // 17408 x 768
  bf16* h_bf = P;                       // 17408 x 1024
  float* y2 = xn;

  auto gemm = [&](const bf16* A, const bf16* W, const float* bias,
                  const float* res, float* oF, bf16* oB, int M, int N, int K,
                  int flags) {
    dim3 g(M / 128, N / 128);
    k_mfma_gemm<<<g, 256, 0, stream>>>(A, W, bias, res, oF, oB, M, N, K, flags);
  };

  // ---- weight conversion (one launch) ----
  {
    CvtTab t;
    for (int i = 0; i < 2; ++i) {
      const size_t om = (size_t)i * kC * kC;
      const float* s3[3] = {jq_w + om, jk_w + om, jv_w + om};
      bf16* d3[3] = {Wjqkv + (size_t)i * 768 * 256,
                     Wjqkv + (size_t)i * 768 * 256 + 65536,
                     Wjqkv + (size_t)i * 768 * 256 + 131072};
      for (int j = 0; j < 3; ++j) {
        t.src[i * 3 + j] = s3[j];
        t.dst[i * 3 + j] = d3[j];
        t.n[i * 3 + j] = 65536;
      }
    }
    // Wkv4 = [k0 | v0 | k1 | v1]
    t.src[6] = jk_w;                 t.dst[6] = Wkv4;               t.n[6] = 65536;
    t.src[7] = jv_w;                 t.dst[7] = Wkv4 + 65536;       t.n[7] = 65536;
    t.src[8] = jk_w + (size_t)65536; t.dst[8] = Wkv4 + 131072;      t.n[8] = 65536;
    t.src[9] = jv_w + (size_t)65536; t.dst[9] = Wkv4 + 196608;      t.n[9] = 65536;
    t.src[10] = jf1_w; t.dst[10] = Wjf1; t.n[10] = 2 * 1024 * 256;
    t.src[11] = jf2_w; t.dst[11] = Wjf2; t.n[11] = 2 * 256 * 1024;
    k_cvt_multi<<<dim3(512, 12), 256, 0, stream>>>(t);
  }
  {
    BiasTab t;
    for (int i = 0; i < 2; ++i) {
      t.src[i * 3 + 0] = jq_b + (size_t)i * kC;
      t.src[i * 3 + 1] = jk_b + (size_t)i * kC;
      t.src[i * 3 + 2] = jv_b + (size_t)i * kC;
      t.dst[i * 3 + 0] = cb_jqkv + i * 768;
      t.dst[i * 3 + 1] = cb_jqkv + i * 768 + 256;
      t.dst[i * 3 + 2] = cb_jqkv + i * 768 + 512;
    }
    t.src[6] = jk_b;       t.dst[6] = cb_kv4;
    t.src[7] = jv_b;       t.dst[7] = cb_kv4 + 256;
    t.src[8] = jk_b + kC;  t.dst[8] = cb_kv4 + 512;
    t.src[9] = jv_b + kC;  t.dst[9] = cb_kv4 + 768;
    k_bias_cat<<<10, 256, 0, stream>>>(t);
  }

  k_xform_in<<<dim3(8, 8, 4 * kV), 256, 0, stream>>>(data, nodes, embsX_bf);
  k_relay_init<<<kBT / 4, 256, 0, stream>>>(nodes, relay0_bf);

  // hoisted: K/V projections of [embs; relay0] for BOTH layers, one GEMM
  gemm(embsX_bf, Wkv4, cb_kv4, nullptr, nullptr, akavBuf, kRowsE, 1024, 256, 4);

  // layer-0 LN (layer-1 LN is fused into layer-0's BN2)
  k_layernorm<<<kRows / 4, 256, 0, stream>>>(nodes, ln_g, ln_b, xn, act_bf);

  for (int i = 0; i < 2; ++i) {
    const size_t ob = (size_t)i * kC, ofb1 = (size_t)i * kDIN;
    const bf16* Wj = Wjqkv + (size_t)i * 768 * 256;
    const bf16* Wf1 = Wjf1 + (size_t)i * 1024 * 256;
    const bf16* Wf2 = Wjf2 + (size_t)i * 256 * 1024;
    const float* cbj = cb_jqkv + i * 768;
    const int nb = kRows / 16;

    gemm(act_bf, Wj, cbj, nullptr, nullptr, qkv_bf, kRows, 768, 256, 4);
    k_attn_sat<<<kRows / 4, 256, 0, stream>>>(qkv_bf, akavBuf + (size_t)i * 512,
                                              xn);  // z = xn + att
    // BN1 -> ret (nodes fp32 + act_bf)
    k_bn_partial<<<nb, 256, 0, stream>>>(xn, part, nb);
    k_bn_finalize<<<kC, 256, 0, stream>>>(part, nb, 1.f / kRows, jbn_g + ob,
                                          jbn_b + ob, scale, shift);
    k_bn_apply<<<kRows / 4, 256, 0, stream>>>(xn, scale, shift, nodes, act_bf,
                                              0);
    gemm(act_bf, Wf1, jf1_b + ofb1, nullptr, nullptr, h_bf, kRows, 1024, 256,
         4 | 1);
    gemm(h_bf, Wf2, jf2_b + ob, nodes, y2, nullptr, kRows, 256, 1024, 2);
    // BN2 stats on y2
    k_bn_partial<<<nb, 256, 0, stream>>>(y2, part, nb);
    k_bn_finalize<<<kC, 256, 0, stream>>>(part, nb, 1.f / kRows, jfbn_g + ob,
                                          jfbn_b + ob, scale, shift);
    if (i == 0) {
      // fused BN2(leaky) + layer-1 LN
      k_bn_ln<<<kRows / 4, 256, 0, stream>>>(y2, scale, shift, ln_g + kC,
                                             ln_b + kC, nodes, xn, act_bf);
    } else {
      k_bn_apply<<<kRows / 4, 256, 0, stream>>>(y2, scale, shift, nodes,
                                                nullptr, 1);
    }
  }

  k_xform_out<<<dim3(8, 8, 4 * kV), 256, 0, stream>>>(nodes, out);
  (void)in_sizes; (void)n_in; (void)out_size; (void)ws_size;
}